// Round 15
// baseline (2237.206 us; speedup 1.0000x reference)
//
#include <hip/hip_runtime.h>
#include <hip/hip_bf16.h>

#define D_MODEL 2048
#define NHEAD   16
#define DK      128
#define BB      4
#define SS      2048
#define MTOT    (BB*SS)   // 8192 rows

typedef __bf16 bf16x8 __attribute__((ext_vector_type(8)));
typedef float  f32x4  __attribute__((ext_vector_type(4)));
typedef unsigned short u16x4 __attribute__((ext_vector_type(4)));
typedef unsigned short u16x8 __attribute__((ext_vector_type(8)));

static __device__ __forceinline__ unsigned short f2bf(float f) {
    __hip_bfloat16 h = __float2bfloat16(f);
    return __builtin_bit_cast(unsigned short, h);
}
static __device__ __forceinline__ float bf2f(unsigned short u) {
    __hip_bfloat16 h = __builtin_bit_cast(__hip_bfloat16, u);
    return __bfloat162float(h);
}
// async global->LDS, 16B per lane; LDS dest = wave-uniform base + lane*16
static __device__ __forceinline__ void glds16(const void* g, void* l) {
    __builtin_amdgcn_global_load_lds(
        (const __attribute__((address_space(1))) unsigned int*)g,
        (__attribute__((address_space(3))) unsigned int*)l, 16, 0, 0);
}
static __device__ __forceinline__ bf16x8 ldsld(const unsigned short* p) {
    return __builtin_bit_cast(bf16x8, *reinterpret_cast<const u16x8*>(p));
}

// ---------------- fp32 -> bf16 conversion: all 5 inputs in one launch -------
__global__ void cvt_all(const float* __restrict__ x,  const float* __restrict__ wq,
                        const float* __restrict__ wk, const float* __restrict__ wv,
                        const float* __restrict__ wo,
                        unsigned short* __restrict__ xb,
                        unsigned short* __restrict__ wqkv,
                        unsigned short* __restrict__ wob) {
    const int N4X = 4194304;   // XN/4
    const int N4W = 1048576;   // WN/4
    int i = blockIdx.x * 256 + threadIdx.x;
    const float* src; unsigned short* dst; int off;
    if (i < N4X) { src = x; dst = xb; off = i; }
    else {
        int j = i - N4X;
        int which = j >> 20;           // /N4W
        off = j & (N4W - 1);
        src = (which == 0) ? wq : (which == 1) ? wk : (which == 2) ? wv : wo;
        dst = (which == 3) ? wob : wqkv + (size_t)which * 4194304;  // WN elems
    }
    float4 v = reinterpret_cast<const float4*>(src)[off];
    u16x4 o;
    o[0] = f2bf(v.x); o[1] = f2bf(v.y); o[2] = f2bf(v.z); o[3] = f2bf(v.w);
    reinterpret_cast<u16x4*>(dst)[off] = o;
}

// ---------------- GEMM: C = A[M][K] * B[N][K]^T ------------------------------
// r11 4-phase interleave + 5-SLOT LDS ROTATION (80KB -> 2 blocks/CU):
// unit u = {Ak0,Bk0,Ak1,Bk1}(t) at slot (u%5)*16KB; one unit staged per phase,
// lead L=3 (phase P stages unit P+3). Overwrite safety: slot's prev occupant
// u-5 last read at P-1 (pre-barrier) or P-3 -> always barrier-separated
// (verified for all P mod 4). vmcnt in LOADS: outstanding <= 3 units = 6;
// allow newest unit -> vmcnt(2) at both syncs; last-tile khalf1 -> vmcnt(0).
// 2D-chunk XCD swizzle (r14). OUT_MODE 0: merged QKV + fused RoPE epilogue;
// OUT_MODE 1: fp32 row-major.
#define GBM 256
#define GBN 256
#define GBK 64

template<int OUT_MODE>
__global__ __launch_bounds__(512, 4) void gemm_bt(
    const unsigned short* __restrict__ A,
    const unsigned short* __restrict__ B,
    void* __restrict__ C,
    const int* __restrict__ pos,
    int M, int N, int K)
{
    __shared__ unsigned short sm[40960];    // 80 KiB = 5 slots x 8192 elems
    const int t = threadIdx.x;
    const int lane = t & 63, w = t >> 6;
    const int wr = w >> 2, wc = w & 3;      // 2 x 4 wave grid, 128x64 out/wave
    const int li = lane & 15, lg = lane >> 4;

    // XCD 2D-chunk swizzle (dispatch round-robins XCD ~ lin%8)
    int lin = blockIdx.y * gridDim.x + blockIdx.x;
    const int xcd = lin & 7, idx = lin >> 3;
    int bm, bn;
    if (OUT_MODE == 0) {        // grid 24x32: chunks 8bm x 12bn, 96 blocks/XCD
        bm = (xcd >> 1) * 8 + idx / 12;
        bn = (xcd & 1) * 12 + idx % 12;
    } else {                    // grid 8x32: chunks 4bm x 8bn, 32 blocks/XCD
        bm = xcd * 4 + (idx >> 3);
        bn = idx & 7;
    }

    f32x4 acc[8][4] = {};
    const size_t rowA0 = (size_t)bm * GBM, rowB0 = (size_t)bn * GBN;
    const unsigned short* Abase = A + rowA0 * K;
    const unsigned short* Bbase = B + rowB0 * K;

    const int nt = K / GBK;
    const int nu = 4 * nt;

    // stage unit u into slot (u%5): 1024 granules, 512 thr x 2 glds
    auto stageUnit = [&](int u) {
        if (u >= nu) return;
        const int ttu = u >> 2, j = u & 3;
        const int ko = ttu * GBK + (j >> 1) * 32;
        const unsigned short* S = (j & 1) ? Bbase : Abase;
        const int slot = (u % 5) * 8192;
        #pragma unroll
        for (int c = 0; c < 2; ++c) {
            const int idx0 = (c * 8 + w) * 64;          // wave-uniform granule base
            const int gidx = idx0 + lane;
            const int R = gidx >> 2;                    // 0..255
            const int glog = (gidx & 3) ^ ((R >> 1) & 3);
            glds16(S + (size_t)R * K + ko + glog * 8, &sm[slot + idx0 * 8]);
        }
    };

    // prologue: units 0,1,2
    stageUnit(0); stageUnit(1); stageUnit(2);

    #pragma unroll 1
    for (int tt = 0; tt < nt; ++tt) {
        const int P0 = 4 * tt;
        const int sA0 = ((P0    ) % 5) * 8192;
        const int sB0 = ((P0 + 1) % 5) * 8192;
        const int sA1 = ((P0 + 2) % 5) * 8192;
        const int sB1 = ((P0 + 3) % 5) * 8192;
        bf16x8 bfr[4], af[4];

        // ======== k-half 0 sync: Ak0,Bk0 landed (newest unit may remain) ====
        asm volatile("s_waitcnt vmcnt(2)" ::: "memory");
        __builtin_amdgcn_s_barrier();
        asm volatile("" ::: "memory");
        __builtin_amdgcn_sched_barrier(0);

        // ---- p0: m-half 0, k0 ----
        stageUnit(P0 + 3);
        #pragma unroll
        for (int cf = 0; cf < 4; ++cf) {
            const int R = wc*64 + cf*16 + li;
            bfr[cf] = ldsld(&sm[sB0 + R*32 + ((lg ^ ((R >> 1) & 3)) * 8)]);
        }
        #pragma unroll
        for (int f = 0; f < 4; ++f) {
            const int R = wr*128 + f*16 + li;
            af[f] = ldsld(&sm[sA0 + R*32 + ((lg ^ ((R >> 1) & 3)) * 8)]);
        }
        __builtin_amdgcn_s_setprio(1);
        #pragma unroll
        for (int f = 0; f < 4; ++f)
            #pragma unroll
            for (int cf = 0; cf < 4; ++cf)
                acc[f][cf] = __builtin_amdgcn_mfma_f32_16x16x32_bf16(af[f], bfr[cf], acc[f][cf], 0, 0, 0);
        __builtin_amdgcn_s_setprio(0);

        // ---- p1: m-half 1, k0 (bfr reused) ----
        stageUnit(P0 + 4);
        #pragma unroll
        for (int f = 0; f < 4; ++f) {
            const int R = wr*128 + 64 + f*16 + li;
            af[f] = ldsld(&sm[sA0 + R*32 + ((lg ^ ((R >> 1) & 3)) * 8)]);
        }
        __builtin_amdgcn_s_setprio(1);
        #pragma unroll
        for (int f = 0; f < 4; ++f)
            #pragma unroll
            for (int cf = 0; cf < 4; ++cf)
                acc[4+f][cf] = __builtin_amdgcn_mfma_f32_16x16x32_bf16(af[f], bfr[cf], acc[4+f][cf], 0, 0, 0);
        __builtin_amdgcn_s_setprio(0);

        // ======== k-half 1 sync: Ak1,Bk1 landed ========
        if (tt < nt - 1) { asm volatile("s_waitcnt vmcnt(2)" ::: "memory"); }
        else             { asm volatile("s_waitcnt vmcnt(0)" ::: "memory"); }
        __builtin_amdgcn_s_barrier();
        asm volatile("" ::: "memory");
        __builtin_amdgcn_sched_barrier(0);

        // ---- p2: m-half 0, k1 ----
        stageUnit(P0 + 5);
        #pragma unroll
        for (int cf = 0; cf < 4; ++cf) {
            const int R = wc*64 + cf*16 + li;
            bfr[cf] = ldsld(&sm[sB1 + R*32 + ((lg ^ ((R >> 1) & 3)) * 8)]);
        }
        #pragma unroll
        for (int f = 0; f < 4; ++f) {
            const int R = wr*128 + f*16 + li;
            af[f] = ldsld(&sm[sA1 + R*32 + ((lg ^ ((R >> 1) & 3)) * 8)]);
        }
        __builtin_amdgcn_s_setprio(1);
        #pragma unroll
        for (int f = 0; f < 4; ++f)
            #pragma unroll
            for (int cf = 0; cf < 4; ++cf)
                acc[f][cf] = __builtin_amdgcn_mfma_f32_16x16x32_bf16(af[f], bfr[cf], acc[f][cf], 0, 0, 0);
        __builtin_amdgcn_s_setprio(0);

        // ---- p3: m-half 1, k1 ----
        stageUnit(P0 + 6);
        #pragma unroll
        for (int f = 0; f < 4; ++f) {
            const int R = wr*128 + 64 + f*16 + li;
            af[f] = ldsld(&sm[sA1 + R*32 + ((lg ^ ((R >> 1) & 3)) * 8)]);
        }
        __builtin_amdgcn_s_setprio(1);
        #pragma unroll
        for (int f = 0; f < 4; ++f)
            #pragma unroll
            for (int cf = 0; cf < 4; ++cf)
                acc[4+f][cf] = __builtin_amdgcn_mfma_f32_16x16x32_bf16(af[f], bfr[cf], acc[4+f][cf], 0, 0, 0);
        __builtin_amdgcn_s_setprio(0);
    }

    // epilogue: D row = (lane>>4)*4 + reg, col = lane&15
    if (OUT_MODE == 0) {
        // fused RoPE on q,k: pair (dk, dk^1) lives in lanes (li, li^1)
        float freqs[4];
        #pragma unroll
        for (int cf = 0; cf < 4; ++cf) {
            int dk = (wc*64 + cf*16 + li) & 127;
            freqs[cf] = exp2f(-0.207620498f * (float)(dk >> 1)); // theta^(-2p/128)
        }
        #pragma unroll
        for (int mr = 0; mr < 8; ++mr) {
            #pragma unroll
            for (int r = 0; r < 4; ++r) {
                int row = (int)rowA0 + wr*128 + mr*16 + lg*4 + r;
                int b = row >> 11, s = row & (SS - 1);
                float ps = (float)pos[s];
                #pragma unroll
                for (int cf = 0; cf < 4; ++cf) {
                    int col = (int)rowB0 + wc*64 + cf*16 + li;
                    float v = acc[mr][cf][r];
                    float vp = __shfl_xor(v, 1, 64);   // partner (dk^1) value
                    int mat = col >> 11;               // 0=q 1=k 2=v
                    int c2  = col & 2047;
                    int h = c2 >> 7, dk = c2 & (DK - 1);
                    if (mat < 2) {
                        float ang = ps * freqs[cf];
                        float sn = __sinf(ang), cs = __cosf(ang);
                        v = (dk & 1) ? (vp * sn + v * cs) : (v * cs - vp * sn);
                    }
                    ((unsigned short*)C)[(size_t)mat * ((size_t)MTOT * D_MODEL)
                        + ((((size_t)b*NHEAD + h)*SS + s) << 7) + dk] = f2bf(v);
                }
            }
        }
    } else {
        #pragma unroll
        for (int mr = 0; mr < 8; ++mr)
            #pragma unroll
            for (int cf = 0; cf < 4; ++cf)
                #pragma unroll
                for (int r = 0; r < 4; ++r) {
                    int row = (int)rowA0 + wr*128 + mr*16 + lg*4 + r;
                    int col = (int)rowB0 + wc*64 + cf*16 + li;
                    ((float*)C)[(size_t)row * N + col] = acc[mr][cf][r];
                }
    }
}

// ---------------- flash attention v5 (unchanged) -----------------------------
#define QB   128
#define WQ   32
#define KVB  64
#define KSZ  (KVB * DK)         // 8192 elems per K buffer

__global__ __launch_bounds__(256, 2) void attn_kernel(
    const unsigned short* __restrict__ Q,   // [B*H][S][DK]
    const unsigned short* __restrict__ K,
    const unsigned short* __restrict__ V,
    unsigned short* __restrict__ AO)        // [B][S][NHEAD*DK]
{
    __shared__ unsigned short lds[40960];   // 80 KiB: K dbuf 32K | Vt dbuf 32K | P 16K
    unsigned short* Pl = lds + 32768;

    const int i0 = blockIdx.y * gridDim.x + blockIdx.x;
    const int bx = (i0 >> 3) & 7;
    const int bh = (i0 & 7) * 8 + (i0 >> 6);
    const int b = bh >> 4, h = bh & 15;
    const int t = threadIdx.x;
    const int lane = t & 63, w = t >> 6;
    const int li = lane & 15, lg = lane >> 4;

    const unsigned short* Qb = Q + ((size_t)bh * SS << 7);
    const unsigned short* Kb = K + ((size_t)bh * SS << 7);
    const unsigned short* Vb = V + ((size_t)bh * SS << 7);
    const float SCL = 0.08838834764831845f; // 1/sqrt(128)

    u16x8 vreg[4];

    #pragma unroll 1
    for (int qi = 0; qi < 2; ++qi) {
        const int qt = qi ? (15 - bx) : bx;
        const int q0 = qt * QB;
        const int qw = q0 + w * WQ;

        bf16x8 qa[2][4];
        #pragma unroll
        for (int rf = 0; rf < 2; ++rf)
            #pragma unroll
            for (int kq = 0; kq < 4; ++kq)
                qa[rf][kq] = __builtin_bit_cast(bf16x8,
                    *reinterpret_cast<const u16x8*>(&Qb[((size_t)(qw + rf*16 + li) << 7) + kq*32 + lg*8]));

        f32x4 oacc[2][8] = {};
        float lpart[2][4] = {};
        const int nt = (q0 + QB) / KVB;

        auto stageK = [&](int kv0, int which) {
            #pragma unroll
            for (int i = 0; i < 4; ++i) {
                const int slot0 = which * 1024 + i * 256 + w * 64;
                const int row = i * 16 + w * 4 + (lane >> 4);
                const int csrc = (lane & 15) ^ (row & 7);
                glds16(Kb + (((size_t)(kv0 + row)) << 7) + csrc * 8, &lds[slot0 * 8]);
            }
        };
        auto loadV = [&](int kv0) {
            const int row = lane;
            #pragma unroll
            for (int i = 0; i < 4; ++i) {
                const int dc = w + i * 4;
                vreg[i] = *reinterpret_cast<const u16x8*>(&Vb[(((size_t)(kv0 + row)) << 7) + dc * 8]);
            }
        };
        auto writeV = [&](int vbuf) {
            unsigned short* Vt = lds + 16384 + vbuf * 8192;
            #pragma unroll
            for (int i = 0; i < 4; ++i) {
                const int dc = w + i * 4;
                #pragma unroll
                for (int j = 0; j < 8; ++j) {
                    const int d = dc*8 + j;
                    Vt[d * 64 + (((lane >> 3) ^ (d & 7)) * 8) + (lane & 7)] = vreg[i][j];
                }
            }
        };

        stageK(0, 0);
        loadV(0);
        __syncthreads();
        writeV(0);
        __syncthreads();

        #pragma unroll 1
        for (int tt = 0; tt < nt; ++tt) {
            const int kv0 = tt * KVB;
            unsigned short* Kc = lds + (size_t)(tt & 1) * KSZ;
            const unsigned short* Vt = lds + 16384 + (tt & 1) * 8192;
            if (tt + 1 < nt) { stageK(kv0 + KVB, (tt & 1) ^ 1); loadV(kv0 + KVB); }

            if (kv0 <= qw + WQ - 1) {
                f32x4 sv[2][4] = {};
                __builtin_amdgcn_s_setprio(1);
                #pragma unroll
                for (int cf = 0; cf < 4; ++cf) {
                    const int krow = cf*16 + li;
                    #pragma unroll
                    for (int kq = 0; kq < 4; ++kq) {
                        bf16x8 kb = __builtin_bit_cast(bf16x8,
                            *reinterpret_cast<const u16x8*>(&Kc[krow * DK + (((kq*4 + lg) ^ (li & 7)) * 8)]));
                        #pragma unroll
                        for (int rf = 0; rf < 2; ++rf)
                            sv[rf][cf] = __builtin_amdgcn_mfma_f32_16x16x32_bf16(qa[rf][kq], kb, sv[rf][cf], 0, 0, 0);
                    }
                }
                __builtin_amdgcn_s_setprio(0);
                const bool diag = (kv0 + KVB - 1 > qw);
                #pragma unroll
                for (int rf = 0; rf < 2; ++rf)
                    #pragma unroll
                    for (int cf = 0; cf < 4; ++cf)
                        #pragma unroll
                        for (int r = 0; r < 4; ++r) {
                            float p = __expf(sv[rf][cf][r] * SCL);
                            if (diag) {
                                int rowg = qw + rf*16 + lg*4 + r;
                                int colg = kv0 + cf*16 + li;
                                p = (colg <= rowg) ? p : 0.0f;
                            }
                            sv[rf][cf][r] = p;
                            lpart[rf][r] += p;
                        }
                unsigned short* Pw = Pl + w * (WQ * 64);
                #pragma unroll
                for (int rf = 0; rf < 2; ++rf)
                    #pragma unroll
                    for (int cf = 0; cf < 4; ++cf)
                        #pragma unroll
                        for (int r = 0; r < 4; ++r) {
                            const int qr = rf*16 + lg*4 + r;
                            Pw[qr * 64 + (((cf*2 + (li >> 3)) ^ (qr & 7)) * 8) + (li & 7)] = f2bf(sv[rf][cf][r]);
                        }
                bf16x8 pa[2][2];
                #pragma unroll
                for (int rf = 0; rf < 2; ++rf)
                    #pragma unroll
                    for (int kc = 0; kc < 2; ++kc)
                        pa[rf][kc] = __builtin_bit_cast(bf16x8,
                            *reinterpret_cast<const u16x8*>(&Pw[(rf*16 + li) * 64 + (((kc*4 + lg) ^ (li & 7)) * 8)]));
                __builtin_amdgcn_s_setprio(1);
                #pragma unroll
                for (int g = 0; g < 8; ++g) {
                    const int vrow = g*16 + li;
                    bf16x8 vb0 = __builtin_bit_cast(bf16x8,
                        *reinterpret_cast<const u16x8*>(&Vt[vrow * 64 + ((lg ^ (li & 7)) * 8)]));
                    bf16x8 vb1 = __builtin_bit_cast(bf16x8,
                        *reinterpret_cast<const u16x8*>(&Vt[vrow * 64 + (((4 + lg) ^ (li & 7)) * 8)]));
                    #pragma unroll
                    for (int rf = 0; rf < 2; ++rf) {
                        oacc[rf][g] = __builtin_amdgcn_mfma_f32_16x16x32_bf16(pa[rf][0], vb0, oacc[rf][g], 0, 0, 0);
                        oacc[rf][g] = __builtin_amdgcn_mfma_f32_16x16x32_bf16(pa[rf][1], vb1, oacc[rf][g], 0, 0, 0);
                    }
                }
                __builtin_amdgcn_s_setprio(0);
            }

            if (tt + 1 < nt) writeV((tt + 1) & 1);
            __syncthreads();
        }

        float ls[2][4];
        #pragma unroll
        for (int rf = 0; rf < 2; ++rf)
            #pragma unroll
            for (int r = 0; r < 4; ++r) {
                float s = lpart[rf][r];
                s += __shfl_xor(s, 1, 64);
                s += __shfl_xor(s, 2, 64);
                s += __shfl_xor(s, 4, 64);
                s += __shfl_xor(s, 8, 64);
                ls[rf][r] = 1.0f / s;
            }
        #pragma unroll
        for (int rf = 0; rf < 2; ++rf)
            #pragma unroll
            for (int g = 0; g < 8; ++g)
                #pragma unroll
                for (int r = 0; r < 4; ++r) {
                    int s = qw + rf*16 + lg*4 + r;
                    int d = g*16 + li;
                    AO[((size_t)b * SS + s) * D_MODEL + h*DK + d] = f2bf(oacc[rf][g][r] * ls[rf][r]);
                }
    }
}

// ---------------- host ----------------
extern "C" void kernel_launch(void* const* d_in, const int* in_sizes, int n_in,
                              void* d_out, int out_size, void* d_ws, size_t ws_size,
                              hipStream_t stream) {
    const float* x  = (const float*)d_in[0];
    const float* wq = (const float*)d_in[1];
    const float* wk = (const float*)d_in[2];
    const float* wv = (const float*)d_in[3];
    const float* wo = (const float*)d_in[4];
    const int* pos  = (const int*)d_in[5];

    char* ws = (char*)d_ws;
    size_t off = 0;
    auto alloc = [&](size_t bytes) {
        void* p = ws + off;
        off += (bytes + 255) & ~(size_t)255;
        return p;
    };
    const size_t XN = (size_t)MTOT * D_MODEL;   // 16,777,216
    const size_t WN = (size_t)D_MODEL * D_MODEL;
    unsigned short* xb    = (unsigned short*)alloc(XN * 2);
    unsigned short* wqkvb = (unsigned short*)alloc(3 * WN * 2);
    unsigned short* wob   = (unsigned short*)alloc(WN * 2);
    unsigned short* qkvb  = (unsigned short*)alloc(3 * XN * 2);
    unsigned short* qb = qkvb, *kb = qkvb + XN, *vb = qkvb + 2*XN;
    unsigned short* ao = xb;   // alias: xb dead after QKV GEMM

    cvt_all<<<32768, 256, 0, stream>>>(x, wq, wk, wv, wo, xb, wqkvb, wob);

    // merged QKV projection + fused RoPE: N = 6144, grid (24, 32) = 768 blocks
    gemm_bt<0><<<dim3(3*D_MODEL / GBN, MTOT / GBM), 512, 0, stream>>>(
        xb, wqkvb, qkvb, pos, MTOT, 3*D_MODEL, D_MODEL);

    attn_kernel<<<dim3(8, 64), 256, 0, stream>>>(qb, kb, vb, ao);

    gemm_bt<1><<<dim3(D_MODEL / GBN, MTOT / GBM), 512, 0, stream>>>(
        ao, wob, d_out, pos, MTOT, D_MODEL, D_MODEL);
}

// Round 16
// 405.445 us; speedup vs baseline: 5.5179x; 5.5179x over previous
//
#include <hip/hip_runtime.h>
#include <hip/hip_bf16.h>

#define D_MODEL 2048
#define NHEAD   16
#define DK      128
#define BB      4
#define SS      2048
#define MTOT    (BB*SS)   // 8192 rows

typedef __bf16 bf16x8 __attribute__((ext_vector_type(8)));
typedef float  f32x4  __attribute__((ext_vector_type(4)));
typedef unsigned short u16x4 __attribute__((ext_vector_type(4)));
typedef unsigned short u16x8 __attribute__((ext_vector_type(8)));

static __device__ __forceinline__ unsigned short f2bf(float f) {
    __hip_bfloat16 h = __float2bfloat16(f);
    return __builtin_bit_cast(unsigned short, h);
}
static __device__ __forceinline__ float bf2f(unsigned short u) {
    __hip_bfloat16 h = __builtin_bit_cast(__hip_bfloat16, u);
    return __bfloat162float(h);
}
// async global->LDS, 16B per lane; LDS dest = wave-uniform base + lane*16
static __device__ __forceinline__ void glds16(const void* g, void* l) {
    __builtin_amdgcn_global_load_lds(
        (const __attribute__((address_space(1))) unsigned int*)g,
        (__attribute__((address_space(3))) unsigned int*)l, 16, 0, 0);
}
static __device__ __forceinline__ bf16x8 ldsld(const unsigned short* p) {
    return __builtin_bit_cast(bf16x8, *reinterpret_cast<const u16x8*>(p));
}

// ---------------- fp32 -> bf16 conversion: all 5 inputs in one launch -------
__global__ void cvt_all(const float* __restrict__ x,  const float* __restrict__ wq,
                        const float* __restrict__ wk, const float* __restrict__ wv,
                        const float* __restrict__ wo,
                        unsigned short* __restrict__ xb,
                        unsigned short* __restrict__ wqkv,
                        unsigned short* __restrict__ wob) {
    const int N4X = 4194304;   // XN/4
    const int N4W = 1048576;   // WN/4
    int i = blockIdx.x * 256 + threadIdx.x;
    const float* src; unsigned short* dst; int off;
    if (i < N4X) { src = x; dst = xb; off = i; }
    else {
        int j = i - N4X;
        int which = j >> 20;           // /N4W
        off = j & (N4W - 1);
        src = (which == 0) ? wq : (which == 1) ? wk : (which == 2) ? wv : wo;
        dst = (which == 3) ? wob : wqkv + (size_t)which * 4194304;  // WN elems
    }
    float4 v = reinterpret_cast<const float4*>(src)[off];
    u16x4 o;
    o[0] = f2bf(v.x); o[1] = f2bf(v.y); o[2] = f2bf(v.z); o[3] = f2bf(v.w);
    reinterpret_cast<u16x4*>(dst)[off] = o;
}

// ---------------- GEMM: C = A[M][K] * B[N][K]^T ------------------------------
// r14 EXACT configuration (best measured: QKV 205us, MfmaUtil 46%):
// 256x256 tile, BK=64, 8 waves, 4-phase/K-tile interleaved, 128KB LDS =
// 8 slots x 16KB, sync at p0/p2 {vmcnt(4)+raw s_barrier} (tail vmcnt(0)),
// stage-inside-phase, setprio, both-sides granule swizzle, 2D-chunk XCD
// swizzle. NOTE r15 lesson: 2 blocks/CU is IMPOSSIBLE here — acc alone is
// 128 regs; __launch_bounds__(512,4) forced 64-reg cap -> spills -> 9x slower.
// OUT_MODE 0: merged QKV epilogue (N=6144) -> bf16 [mat][b][h][s][dk] with
//             FUSED RoPE on q,k. OUT_MODE 1: fp32 row-major [M][N]
#define GBM 256
#define GBN 256
#define GBK 64

template<int OUT_MODE>
__global__ __launch_bounds__(512) void gemm_bt(
    const unsigned short* __restrict__ A,
    const unsigned short* __restrict__ B,
    void* __restrict__ C,
    const int* __restrict__ pos,
    int M, int N, int K)
{
    __shared__ unsigned short sm[65536];    // 128 KiB = 8 slots x 8192 elems
    const int t = threadIdx.x;
    const int lane = t & 63, w = t >> 6;
    const int wr = w >> 2, wc = w & 3;      // 2 x 4 wave grid, 128x64 out/wave
    const int li = lane & 15, lg = lane >> 4;

    // XCD 2D-chunk swizzle (dispatch round-robins XCD ~ lin%8)
    int lin = blockIdx.y * gridDim.x + blockIdx.x;
    const int xcd = lin & 7, idx = lin >> 3;
    int bm, bn;
    if (OUT_MODE == 0) {        // grid 24x32: chunks 8bm x 12bn, 96 blocks/XCD
        bm = (xcd >> 1) * 8 + idx / 12;
        bn = (xcd & 1) * 12 + idx % 12;
    } else {                    // grid 8x32: chunks 4bm x 8bn, 32 blocks/XCD
        bm = xcd * 4 + (idx >> 3);
        bn = idx & 7;
    }

    f32x4 acc[8][4] = {};
    const size_t rowA0 = (size_t)bm * GBM, rowB0 = (size_t)bn * GBN;
    const unsigned short* Abase = A + rowA0 * K;
    const unsigned short* Bbase = B + rowB0 * K;

    const int nt = K / GBK;
    const int nu = 4 * nt;

    // stage one unit: 8192 elems = 1024 granules; 512 thr x 2 glds
    auto stageUnit = [&](int u) {
        const int ttu = u >> 2, j = u & 3;
        const int ko = ttu * GBK + (j >> 1) * 32;
        const unsigned short* S = (j & 1) ? Bbase : Abase;
        const int slot = (u & 7) * 8192;
        #pragma unroll
        for (int c = 0; c < 2; ++c) {
            const int idx0 = (c * 8 + w) * 64;          // wave-uniform granule base
            const int gidx = idx0 + lane;
            const int R = gidx >> 2;                    // 0..255
            const int glog = (gidx & 3) ^ ((R >> 1) & 3);
            glds16(S + (size_t)R * K + ko + glog * 8, &sm[slot + idx0 * 8]);
        }
    };

    // prologue: tile 0's 4 units
    stageUnit(0); stageUnit(1); stageUnit(2); stageUnit(3);

    #pragma unroll 1
    for (int tt = 0; tt < nt; ++tt) {
        const int u0 = 4 * tt;
        const int sb = (tt & 1) * 32768;    // elems: 4 slots of this tile
        bf16x8 bfr[4], af[4];

        // ======== k-half 0 sync: Ak0,Bk0 landed (all but newest 2 units) ====
        asm volatile("s_waitcnt vmcnt(4)" ::: "memory");
        __builtin_amdgcn_s_barrier();
        asm volatile("" ::: "memory");
        __builtin_amdgcn_sched_barrier(0);

        // ---- p0: m-half 0, k0 ----
        if (u0 + 4 < nu) stageUnit(u0 + 4);
        #pragma unroll
        for (int cf = 0; cf < 4; ++cf) {
            const int R = wc*64 + cf*16 + li;
            bfr[cf] = ldsld(&sm[sb + 8192 + R*32 + ((lg ^ ((R >> 1) & 3)) * 8)]);
        }
        #pragma unroll
        for (int f = 0; f < 4; ++f) {
            const int R = wr*128 + f*16 + li;
            af[f] = ldsld(&sm[sb + R*32 + ((lg ^ ((R >> 1) & 3)) * 8)]);
        }
        __builtin_amdgcn_s_setprio(1);
        #pragma unroll
        for (int f = 0; f < 4; ++f)
            #pragma unroll
            for (int cf = 0; cf < 4; ++cf)
                acc[f][cf] = __builtin_amdgcn_mfma_f32_16x16x32_bf16(af[f], bfr[cf], acc[f][cf], 0, 0, 0);
        __builtin_amdgcn_s_setprio(0);

        // ---- p1: m-half 1, k0 (bfr reused) ----
        if (u0 + 5 < nu) stageUnit(u0 + 5);
        #pragma unroll
        for (int f = 0; f < 4; ++f) {
            const int R = wr*128 + 64 + f*16 + li;
            af[f] = ldsld(&sm[sb + R*32 + ((lg ^ ((R >> 1) & 3)) * 8)]);
        }
        __builtin_amdgcn_s_setprio(1);
        #pragma unroll
        for (int f = 0; f < 4; ++f)
            #pragma unroll
            for (int cf = 0; cf < 4; ++cf)
                acc[4+f][cf] = __builtin_amdgcn_mfma_f32_16x16x32_bf16(af[f], bfr[cf], acc[4+f][cf], 0, 0, 0);
        __builtin_amdgcn_s_setprio(0);

        // ======== k-half 1 sync: Ak1,Bk1 landed ========
        if (tt < nt - 1) { asm volatile("s_waitcnt vmcnt(4)" ::: "memory"); }
        else             { asm volatile("s_waitcnt vmcnt(0)" ::: "memory"); }
        __builtin_amdgcn_s_barrier();
        asm volatile("" ::: "memory");
        __builtin_amdgcn_sched_barrier(0);

        // ---- p2: m-half 0, k1 ----
        if (u0 + 6 < nu) stageUnit(u0 + 6);
        #pragma unroll
        for (int cf = 0; cf < 4; ++cf) {
            const int R = wc*64 + cf*16 + li;
            bfr[cf] = ldsld(&sm[sb + 24576 + R*32 + ((lg ^ ((R >> 1) & 3)) * 8)]);
        }
        #pragma unroll
        for (int f = 0; f < 4; ++f) {
            const int R = wr*128 + f*16 + li;
            af[f] = ldsld(&sm[sb + 16384 + R*32 + ((lg ^ ((R >> 1) & 3)) * 8)]);
        }
        __builtin_amdgcn_s_setprio(1);
        #pragma unroll
        for (int f = 0; f < 4; ++f)
            #pragma unroll
            for (int cf = 0; cf < 4; ++cf)
                acc[f][cf] = __builtin_amdgcn_mfma_f32_16x16x32_bf16(af[f], bfr[cf], acc[f][cf], 0, 0, 0);
        __builtin_amdgcn_s_setprio(0);

        // ---- p3: m-half 1, k1 ----
        if (u0 + 7 < nu) stageUnit(u0 + 7);
        #pragma unroll
        for (int f = 0; f < 4; ++f) {
            const int R = wr*128 + 64 + f*16 + li;
            af[f] = ldsld(&sm[sb + 16384 + R*32 + ((lg ^ ((R >> 1) & 3)) * 8)]);
        }
        __builtin_amdgcn_s_setprio(1);
        #pragma unroll
        for (int f = 0; f < 4; ++f)
            #pragma unroll
            for (int cf = 0; cf < 4; ++cf)
                acc[4+f][cf] = __builtin_amdgcn_mfma_f32_16x16x32_bf16(af[f], bfr[cf], acc[4+f][cf], 0, 0, 0);
        __builtin_amdgcn_s_setprio(0);
    }

    // epilogue: D row = (lane>>4)*4 + reg, col = lane&15
    if (OUT_MODE == 0) {
        // fused RoPE on q,k: pair (dk, dk^1) lives in lanes (li, li^1)
        float freqs[4];
        #pragma unroll
        for (int cf = 0; cf < 4; ++cf) {
            int dk = (wc*64 + cf*16 + li) & 127;
            freqs[cf] = exp2f(-0.207620498f * (float)(dk >> 1)); // theta^(-2p/128)
        }
        #pragma unroll
        for (int mr = 0; mr < 8; ++mr) {
            #pragma unroll
            for (int r = 0; r < 4; ++r) {
                int row = (int)rowA0 + wr*128 + mr*16 + lg*4 + r;
                int b = row >> 11, s = row & (SS - 1);
                float ps = (float)pos[s];
                #pragma unroll
                for (int cf = 0; cf < 4; ++cf) {
                    int col = (int)rowB0 + wc*64 + cf*16 + li;
                    float v = acc[mr][cf][r];
                    float vp = __shfl_xor(v, 1, 64);   // partner (dk^1) value
                    int mat = col >> 11;               // 0=q 1=k 2=v
                    int c2  = col & 2047;
                    int h = c2 >> 7, dk = c2 & (DK - 1);
                    if (mat < 2) {
                        float ang = ps * freqs[cf];
                        float sn = __sinf(ang), cs = __cosf(ang);
                        v = (dk & 1) ? (vp * sn + v * cs) : (v * cs - vp * sn);
                    }
                    ((unsigned short*)C)[(size_t)mat * ((size_t)MTOT * D_MODEL)
                        + ((((size_t)b*NHEAD + h)*SS + s) << 7) + dk] = f2bf(v);
                }
            }
        }
    } else {
        #pragma unroll
        for (int mr = 0; mr < 8; ++mr)
            #pragma unroll
            for (int cf = 0; cf < 4; ++cf)
                #pragma unroll
                for (int r = 0; r < 4; ++r) {
                    int row = (int)rowA0 + wr*128 + mr*16 + lg*4 + r;
                    int col = (int)rowB0 + wc*64 + cf*16 + li;
                    ((float*)C)[(size_t)row * N + col] = acc[mr][cf][r];
                }
    }
}

// ---------------- flash attention v5 (unchanged) -----------------------------
#define QB   128
#define WQ   32
#define KVB  64
#define KSZ  (KVB * DK)         // 8192 elems per K buffer

__global__ __launch_bounds__(256, 2) void attn_kernel(
    const unsigned short* __restrict__ Q,   // [B*H][S][DK]
    const unsigned short* __restrict__ K,
    const unsigned short* __restrict__ V,
    unsigned short* __restrict__ AO)        // [B][S][NHEAD*DK]
{
    __shared__ unsigned short lds[40960];   // 80 KiB: K dbuf 32K | Vt dbuf 32K | P 16K
    unsigned short* Pl = lds + 32768;

    const int i0 = blockIdx.y * gridDim.x + blockIdx.x;
    const int bx = (i0 >> 3) & 7;
    const int bh = (i0 & 7) * 8 + (i0 >> 6);
    const int b = bh >> 4, h = bh & 15;
    const int t = threadIdx.x;
    const int lane = t & 63, w = t >> 6;
    const int li = lane & 15, lg = lane >> 4;

    const unsigned short* Qb = Q + ((size_t)bh * SS << 7);
    const unsigned short* Kb = K + ((size_t)bh * SS << 7);
    const unsigned short* Vb = V + ((size_t)bh * SS << 7);
    const float SCL = 0.08838834764831845f; // 1/sqrt(128)

    u16x8 vreg[4];

    #pragma unroll 1
    for (int qi = 0; qi < 2; ++qi) {
        const int qt = qi ? (15 - bx) : bx;
        const int q0 = qt * QB;
        const int qw = q0 + w * WQ;

        bf16x8 qa[2][4];
        #pragma unroll
        for (int rf = 0; rf < 2; ++rf)
            #pragma unroll
            for (int kq = 0; kq < 4; ++kq)
                qa[rf][kq] = __builtin_bit_cast(bf16x8,
                    *reinterpret_cast<const u16x8*>(&Qb[((size_t)(qw + rf*16 + li) << 7) + kq*32 + lg*8]));

        f32x4 oacc[2][8] = {};
        float lpart[2][4] = {};
        const int nt = (q0 + QB) / KVB;

        auto stageK = [&](int kv0, int which) {
            #pragma unroll
            for (int i = 0; i < 4; ++i) {
                const int slot0 = which * 1024 + i * 256 + w * 64;
                const int row = i * 16 + w * 4 + (lane >> 4);
                const int csrc = (lane & 15) ^ (row & 7);
                glds16(Kb + (((size_t)(kv0 + row)) << 7) + csrc * 8, &lds[slot0 * 8]);
            }
        };
        auto loadV = [&](int kv0) {
            const int row = lane;
            #pragma unroll
            for (int i = 0; i < 4; ++i) {
                const int dc = w + i * 4;
                vreg[i] = *reinterpret_cast<const u16x8*>(&Vb[(((size_t)(kv0 + row)) << 7) + dc * 8]);
            }
        };
        auto writeV = [&](int vbuf) {
            unsigned short* Vt = lds + 16384 + vbuf * 8192;
            #pragma unroll
            for (int i = 0; i < 4; ++i) {
                const int dc = w + i * 4;
                #pragma unroll
                for (int j = 0; j < 8; ++j) {
                    const int d = dc*8 + j;
                    Vt[d * 64 + (((lane >> 3) ^ (d & 7)) * 8) + (lane & 7)] = vreg[i][j];
                }
            }
        };

        stageK(0, 0);
        loadV(0);
        __syncthreads();
        writeV(0);
        __syncthreads();

        #pragma unroll 1
        for (int tt = 0; tt < nt; ++tt) {
            const int kv0 = tt * KVB;
            unsigned short* Kc = lds + (size_t)(tt & 1) * KSZ;
            const unsigned short* Vt = lds + 16384 + (tt & 1) * 8192;
            if (tt + 1 < nt) { stageK(kv0 + KVB, (tt & 1) ^ 1); loadV(kv0 + KVB); }

            if (kv0 <= qw + WQ - 1) {
                f32x4 sv[2][4] = {};
                __builtin_amdgcn_s_setprio(1);
                #pragma unroll
                for (int cf = 0; cf < 4; ++cf) {
                    const int krow = cf*16 + li;
                    #pragma unroll
                    for (int kq = 0; kq < 4; ++kq) {
                        bf16x8 kb = __builtin_bit_cast(bf16x8,
                            *reinterpret_cast<const u16x8*>(&Kc[krow * DK + (((kq*4 + lg) ^ (li & 7)) * 8)]));
                        #pragma unroll
                        for (int rf = 0; rf < 2; ++rf)
                            sv[rf][cf] = __builtin_amdgcn_mfma_f32_16x16x32_bf16(qa[rf][kq], kb, sv[rf][cf], 0, 0, 0);
                    }
                }
                __builtin_amdgcn_s_setprio(0);
                const bool diag = (kv0 + KVB - 1 > qw);
                #pragma unroll
                for (int rf = 0; rf < 2; ++rf)
                    #pragma unroll
                    for (int cf = 0; cf < 4; ++cf)
                        #pragma unroll
                        for (int r = 0; r < 4; ++r) {
                            float p = __expf(sv[rf][cf][r] * SCL);
                            if (diag) {
                                int rowg = qw + rf*16 + lg*4 + r;
                                int colg = kv0 + cf*16 + li;
                                p = (colg <= rowg) ? p : 0.0f;
                            }
                            sv[rf][cf][r] = p;
                            lpart[rf][r] += p;
                        }
                unsigned short* Pw = Pl + w * (WQ * 64);
                #pragma unroll
                for (int rf = 0; rf < 2; ++rf)
                    #pragma unroll
                    for (int cf = 0; cf < 4; ++cf)
                        #pragma unroll
                        for (int r = 0; r < 4; ++r) {
                            const int qr = rf*16 + lg*4 + r;
                            Pw[qr * 64 + (((cf*2 + (li >> 3)) ^ (qr & 7)) * 8) + (li & 7)] = f2bf(sv[rf][cf][r]);
                        }
                bf16x8 pa[2][2];
                #pragma unroll
                for (int rf = 0; rf < 2; ++rf)
                    #pragma unroll
                    for (int kc = 0; kc < 2; ++kc)
                        pa[rf][kc] = __builtin_bit_cast(bf16x8,
                            *reinterpret_cast<const u16x8*>(&Pw[(rf*16 + li) * 64 + (((kc*4 + lg) ^ (li & 7)) * 8)]));
                __builtin_amdgcn_s_setprio(1);
                #pragma unroll
                for (int g = 0; g < 8; ++g) {
                    const int vrow = g*16 + li;
                    bf16x8 vb0 = __builtin_bit_cast(bf16x8,
                        *reinterpret_cast<const u16x8*>(&Vt[vrow * 64 + ((lg ^ (li & 7)) * 8)]));
                    bf16x8 vb1 = __builtin_bit_cast(bf16x8,
                        *reinterpret_cast<const u16x8*>(&Vt[vrow * 64 + (((4 + lg) ^ (li & 7)) * 8)]));
                    #pragma unroll
                    for (int rf = 0; rf < 2; ++rf) {
                        oacc[rf][g] = __builtin_amdgcn_mfma_f32_16x16x32_bf16(pa[rf][0], vb0, oacc[rf][g], 0, 0, 0);
                        oacc[rf][g] = __builtin_amdgcn_mfma_f32_16x16x32_bf16(pa[rf][1], vb1, oacc[rf][g], 0, 0, 0);
                    }
                }
                __builtin_amdgcn_s_setprio(0);
            }

            if (tt + 1 < nt) writeV((tt + 1) & 1);
            __syncthreads();
        }

        float ls[2][4];
        #pragma unroll
        for (int rf = 0; rf < 2; ++rf)
            #pragma unroll
            for (int r = 0; r < 4; ++r) {
                float s = lpart[rf][r];
                s += __shfl_xor(s, 1, 64);
                s += __shfl_xor(s, 2, 64);
                s += __shfl_xor(s, 4, 64);
                s += __shfl_xor(s, 8, 64);
                ls[rf][r] = 1.0f / s;
            }
        #pragma unroll
        for (int rf = 0; rf < 2; ++rf)
            #pragma unroll
            for (int g = 0; g < 8; ++g)
                #pragma unroll
                for (int r = 0; r < 4; ++r) {
                    int s = qw + rf*16 + lg*4 + r;
                    int d = g*16 + li;
                    AO[((size_t)b * SS + s) * D_MODEL + h*DK + d] = f2bf(oacc[rf][g][r] * ls[rf][r]);
                }
    }
}

// ---------------- host ----------------
extern "C" void kernel_launch(void* const* d_in, const int* in_sizes, int n_in,
                              void* d_out, int out_size, void* d_ws, size_t ws_size,
                              hipStream_t stream) {
    const float* x  = (const float*)d_in[0];
    const float* wq = (const float*)d_in[1];
    const float* wk = (const float*)d_in[2];
    const float* wv = (const float*)d_in[3];
    const float* wo = (const float*)d_in[4];
    const int* pos  = (const int*)d_in[5];

    char* ws = (char*)d_ws;
    size_t off = 0;
    auto alloc = [&](size_t bytes) {
        void* p = ws + off;
        off += (bytes + 255) & ~(size_t)255;
        return p;
    };
    const size_t XN = (size_t)MTOT * D_MODEL;   // 16,777,216
    const size_t WN = (size_t)D_MODEL * D_MODEL;
    unsigned short* xb    = (unsigned short*)alloc(XN * 2);
    unsigned short* wqkvb = (unsigned short*)alloc(3 * WN * 2);
    unsigned short* wob   = (unsigned short*)alloc(WN * 2);
    unsigned short* qkvb  = (unsigned short*)alloc(3 * XN * 2);
    unsigned short* qb = qkvb, *kb = qkvb + XN, *vb = qkvb + 2*XN;
    unsigned short* ao = xb;   // alias: xb dead after QKV GEMM

    cvt_all<<<32768, 256, 0, stream>>>(x, wq, wk, wv, wo, xb, wqkvb, wob);

    // merged QKV projection + fused RoPE: N = 6144, grid (24, 32) = 768 blocks
    gemm_bt<0><<<dim3(3*D_MODEL / GBN, MTOT / GBM), 512, 0, stream>>>(
        xb, wqkvb, qkvb, pos, MTOT, 3*D_MODEL, D_MODEL);

    attn_kernel<<<dim3(8, 64), 256, 0, stream>>>(qb, kb, vb, ao);

    gemm_bt<1><<<dim3(D_MODEL / GBN, MTOT / GBM), 512, 0, stream>>>(
        ao, wob, d_out, pos, MTOT, D_MODEL, D_MODEL);
}

// Round 17
// 400.202 us; speedup vs baseline: 5.5902x; 1.0131x over previous
//
#include <hip/hip_runtime.h>
#include <hip/hip_bf16.h>

#define D_MODEL 2048
#define NHEAD   16
#define DK      128
#define BB      4
#define SS      2048
#define MTOT    (BB*SS)   // 8192 rows

typedef __bf16 bf16x8 __attribute__((ext_vector_type(8)));
typedef float  f32x4  __attribute__((ext_vector_type(4)));
typedef unsigned short u16x4 __attribute__((ext_vector_type(4)));
typedef unsigned short u16x8 __attribute__((ext_vector_type(8)));

static __device__ __forceinline__ unsigned short f2bf(float f) {
    __hip_bfloat16 h = __float2bfloat16(f);
    return __builtin_bit_cast(unsigned short, h);
}
static __device__ __forceinline__ float bf2f(unsigned short u) {
    __hip_bfloat16 h = __builtin_bit_cast(__hip_bfloat16, u);
    return __bfloat162float(h);
}
// async global->LDS, 16B per lane; LDS dest = wave-uniform base + lane*16
static __device__ __forceinline__ void glds16(const void* g, void* l) {
    __builtin_amdgcn_global_load_lds(
        (const __attribute__((address_space(1))) unsigned int*)g,
        (__attribute__((address_space(3))) unsigned int*)l, 16, 0, 0);
}
static __device__ __forceinline__ bf16x8 ldsld(const unsigned short* p) {
    return __builtin_bit_cast(bf16x8, *reinterpret_cast<const u16x8*>(p));
}

// ---------------- fp32 -> bf16 conversion: all 5 inputs in one launch -------
__global__ void cvt_all(const float* __restrict__ x,  const float* __restrict__ wq,
                        const float* __restrict__ wk, const float* __restrict__ wv,
                        const float* __restrict__ wo,
                        unsigned short* __restrict__ xb,
                        unsigned short* __restrict__ wqkv,
                        unsigned short* __restrict__ wob) {
    const int N4X = 4194304;   // XN/4
    const int N4W = 1048576;   // WN/4
    int i = blockIdx.x * 256 + threadIdx.x;
    const float* src; unsigned short* dst; int off;
    if (i < N4X) { src = x; dst = xb; off = i; }
    else {
        int j = i - N4X;
        int which = j >> 20;           // /N4W
        off = j & (N4W - 1);
        src = (which == 0) ? wq : (which == 1) ? wk : (which == 2) ? wv : wo;
        dst = (which == 3) ? wob : wqkv + (size_t)which * 4194304;  // WN elems
    }
    float4 v = reinterpret_cast<const float4*>(src)[off];
    u16x4 o;
    o[0] = f2bf(v.x); o[1] = f2bf(v.y); o[2] = f2bf(v.z); o[3] = f2bf(v.w);
    reinterpret_cast<u16x4*>(dst)[off] = o;
}

// ---------------- GEMM: C = A[M][K] * B[N][K]^T ------------------------------
// r14/r16 frozen configuration (best of 6 measured structural variants):
// 256x256 tile, BK=64, 8 waves, 4-phase/K-tile interleaved, 128KB LDS =
// 8 slots x 16KB, sync at p0/p2 {vmcnt(4)+raw s_barrier} (tail vmcnt(0)),
// stage-inside-phase, setprio, both-sides granule swizzle, 2D-chunk XCD
// swizzle. (r15 lesson: 2 blocks/CU impossible — acc alone = 128 regs.)
// OUT_MODE 0: merged QKV epilogue (N=6144) -> bf16 [mat][b][h][s][dk] with
//             FUSED RoPE on q,k. OUT_MODE 1: fp32 row-major [M][N]
#define GBM 256
#define GBN 256
#define GBK 64

template<int OUT_MODE>
__global__ __launch_bounds__(512) void gemm_bt(
    const unsigned short* __restrict__ A,
    const unsigned short* __restrict__ B,
    void* __restrict__ C,
    const int* __restrict__ pos,
    int M, int N, int K)
{
    __shared__ unsigned short sm[65536];    // 128 KiB = 8 slots x 8192 elems
    const int t = threadIdx.x;
    const int lane = t & 63, w = t >> 6;
    const int wr = w >> 2, wc = w & 3;      // 2 x 4 wave grid, 128x64 out/wave
    const int li = lane & 15, lg = lane >> 4;

    // XCD 2D-chunk swizzle (dispatch round-robins XCD ~ lin%8)
    int lin = blockIdx.y * gridDim.x + blockIdx.x;
    const int xcd = lin & 7, idx = lin >> 3;
    int bm, bn;
    if (OUT_MODE == 0) {        // grid 24x32: chunks 8bm x 12bn, 96 blocks/XCD
        bm = (xcd >> 1) * 8 + idx / 12;
        bn = (xcd & 1) * 12 + idx % 12;
    } else {                    // grid 8x32: chunks 4bm x 8bn, 32 blocks/XCD
        bm = xcd * 4 + (idx >> 3);
        bn = idx & 7;
    }

    f32x4 acc[8][4] = {};
    const size_t rowA0 = (size_t)bm * GBM, rowB0 = (size_t)bn * GBN;
    const unsigned short* Abase = A + rowA0 * K;
    const unsigned short* Bbase = B + rowB0 * K;

    const int nt = K / GBK;
    const int nu = 4 * nt;

    // stage one unit: 8192 elems = 1024 granules; 512 thr x 2 glds
    auto stageUnit = [&](int u) {
        const int ttu = u >> 2, j = u & 3;
        const int ko = ttu * GBK + (j >> 1) * 32;
        const unsigned short* S = (j & 1) ? Bbase : Abase;
        const int slot = (u & 7) * 8192;
        #pragma unroll
        for (int c = 0; c < 2; ++c) {
            const int idx0 = (c * 8 + w) * 64;          // wave-uniform granule base
            const int gidx = idx0 + lane;
            const int R = gidx >> 2;                    // 0..255
            const int glog = (gidx & 3) ^ ((R >> 1) & 3);
            glds16(S + (size_t)R * K + ko + glog * 8, &sm[slot + idx0 * 8]);
        }
    };

    // prologue: tile 0's 4 units
    stageUnit(0); stageUnit(1); stageUnit(2); stageUnit(3);

    #pragma unroll 1
    for (int tt = 0; tt < nt; ++tt) {
        const int u0 = 4 * tt;
        const int sb = (tt & 1) * 32768;    // elems: 4 slots of this tile
        bf16x8 bfr[4], af[4];

        // ======== k-half 0 sync: Ak0,Bk0 landed ====
        asm volatile("s_waitcnt vmcnt(4)" ::: "memory");
        __builtin_amdgcn_s_barrier();
        asm volatile("" ::: "memory");
        __builtin_amdgcn_sched_barrier(0);

        // ---- p0: m-half 0, k0 ----
        if (u0 + 4 < nu) stageUnit(u0 + 4);
        #pragma unroll
        for (int cf = 0; cf < 4; ++cf) {
            const int R = wc*64 + cf*16 + li;
            bfr[cf] = ldsld(&sm[sb + 8192 + R*32 + ((lg ^ ((R >> 1) & 3)) * 8)]);
        }
        #pragma unroll
        for (int f = 0; f < 4; ++f) {
            const int R = wr*128 + f*16 + li;
            af[f] = ldsld(&sm[sb + R*32 + ((lg ^ ((R >> 1) & 3)) * 8)]);
        }
        __builtin_amdgcn_s_setprio(1);
        #pragma unroll
        for (int f = 0; f < 4; ++f)
            #pragma unroll
            for (int cf = 0; cf < 4; ++cf)
                acc[f][cf] = __builtin_amdgcn_mfma_f32_16x16x32_bf16(af[f], bfr[cf], acc[f][cf], 0, 0, 0);
        __builtin_amdgcn_s_setprio(0);

        // ---- p1: m-half 1, k0 (bfr reused) ----
        if (u0 + 5 < nu) stageUnit(u0 + 5);
        #pragma unroll
        for (int f = 0; f < 4; ++f) {
            const int R = wr*128 + 64 + f*16 + li;
            af[f] = ldsld(&sm[sb + R*32 + ((lg ^ ((R >> 1) & 3)) * 8)]);
        }
        __builtin_amdgcn_s_setprio(1);
        #pragma unroll
        for (int f = 0; f < 4; ++f)
            #pragma unroll
            for (int cf = 0; cf < 4; ++cf)
                acc[4+f][cf] = __builtin_amdgcn_mfma_f32_16x16x32_bf16(af[f], bfr[cf], acc[4+f][cf], 0, 0, 0);
        __builtin_amdgcn_s_setprio(0);

        // ======== k-half 1 sync: Ak1,Bk1 landed ========
        if (tt < nt - 1) { asm volatile("s_waitcnt vmcnt(4)" ::: "memory"); }
        else             { asm volatile("s_waitcnt vmcnt(0)" ::: "memory"); }
        __builtin_amdgcn_s_barrier();
        asm volatile("" ::: "memory");
        __builtin_amdgcn_sched_barrier(0);

        // ---- p2: m-half 0, k1 ----
        if (u0 + 6 < nu) stageUnit(u0 + 6);
        #pragma unroll
        for (int cf = 0; cf < 4; ++cf) {
            const int R = wc*64 + cf*16 + li;
            bfr[cf] = ldsld(&sm[sb + 24576 + R*32 + ((lg ^ ((R >> 1) & 3)) * 8)]);
        }
        #pragma unroll
        for (int f = 0; f < 4; ++f) {
            const int R = wr*128 + f*16 + li;
            af[f] = ldsld(&sm[sb + 16384 + R*32 + ((lg ^ ((R >> 1) & 3)) * 8)]);
        }
        __builtin_amdgcn_s_setprio(1);
        #pragma unroll
        for (int f = 0; f < 4; ++f)
            #pragma unroll
            for (int cf = 0; cf < 4; ++cf)
                acc[f][cf] = __builtin_amdgcn_mfma_f32_16x16x32_bf16(af[f], bfr[cf], acc[f][cf], 0, 0, 0);
        __builtin_amdgcn_s_setprio(0);

        // ---- p3: m-half 1, k1 ----
        if (u0 + 7 < nu) stageUnit(u0 + 7);
        #pragma unroll
        for (int f = 0; f < 4; ++f) {
            const int R = wr*128 + 64 + f*16 + li;
            af[f] = ldsld(&sm[sb + 16384 + R*32 + ((lg ^ ((R >> 1) & 3)) * 8)]);
        }
        __builtin_amdgcn_s_setprio(1);
        #pragma unroll
        for (int f = 0; f < 4; ++f)
            #pragma unroll
            for (int cf = 0; cf < 4; ++cf)
                acc[4+f][cf] = __builtin_amdgcn_mfma_f32_16x16x32_bf16(af[f], bfr[cf], acc[4+f][cf], 0, 0, 0);
        __builtin_amdgcn_s_setprio(0);
    }

    // epilogue: D row = (lane>>4)*4 + reg, col = lane&15
    if (OUT_MODE == 0) {
        float freqs[4];
        #pragma unroll
        for (int cf = 0; cf < 4; ++cf) {
            int dk = (wc*64 + cf*16 + li) & 127;
            freqs[cf] = exp2f(-0.207620498f * (float)(dk >> 1)); // theta^(-2p/128)
        }
        #pragma unroll
        for (int mr = 0; mr < 8; ++mr) {
            #pragma unroll
            for (int r = 0; r < 4; ++r) {
                int row = (int)rowA0 + wr*128 + mr*16 + lg*4 + r;
                int b = row >> 11, s = row & (SS - 1);
                float ps = (float)pos[s];
                #pragma unroll
                for (int cf = 0; cf < 4; ++cf) {
                    int col = (int)rowB0 + wc*64 + cf*16 + li;
                    float v = acc[mr][cf][r];
                    float vp = __shfl_xor(v, 1, 64);   // partner (dk^1) value
                    int mat = col >> 11;               // 0=q 1=k 2=v
                    int c2  = col & 2047;
                    int h = c2 >> 7, dk = c2 & (DK - 1);
                    if (mat < 2) {
                        float ang = ps * freqs[cf];
                        float sn = __sinf(ang), cs = __cosf(ang);
                        v = (dk & 1) ? (vp * sn + v * cs) : (v * cs - vp * sn);
                    }
                    ((unsigned short*)C)[(size_t)mat * ((size_t)MTOT * D_MODEL)
                        + ((((size_t)b*NHEAD + h)*SS + s) << 7) + dk] = f2bf(v);
                }
            }
        }
    } else {
        #pragma unroll
        for (int mr = 0; mr < 8; ++mr)
            #pragma unroll
            for (int cf = 0; cf < 4; ++cf)
                #pragma unroll
                for (int r = 0; r < 4; ++r) {
                    int row = (int)rowA0 + wr*128 + mr*16 + lg*4 + r;
                    int col = (int)rowB0 + wc*64 + cf*16 + li;
                    ((float*)C)[(size_t)row * N + col] = acc[mr][cf][r];
                }
    }
}

// ---------------- flash attention v6: 8 waves/block, QB=256 ------------------
// Same verified inner structure as v5; per-thread staging halved (8 waves
// share one KVB=64 tile): stageK 2 glds, loadV 2 x 16B, writeV 16 scalar
// writes. Paired q-tiles {bx, 7-bx} -> uniform 36 steps/block; 256 blocks,
// 1 block/CU (96KB LDS), 8 waves/CU (same as v5's 2x4).
// Head-grouped XCD map: bh=(i&7)*8+(i>>5), bx=(i>>3)&3 (bijective on [0,256)).
#define QB   256
#define WQ   32
#define KVB  64
#define KSZ  (KVB * DK)         // 8192 elems per K buffer

__global__ __launch_bounds__(512) void attn_kernel(
    const unsigned short* __restrict__ Q,   // [B*H][S][DK]
    const unsigned short* __restrict__ K,
    const unsigned short* __restrict__ V,
    unsigned short* __restrict__ AO)        // [B][S][NHEAD*DK]
{
    __shared__ unsigned short lds[49152];   // 96 KiB: K dbuf 32K | Vt dbuf 32K | P 32K
    unsigned short* Pl = lds + 32768;

    const int i0 = blockIdx.y * gridDim.x + blockIdx.x;
    const int bx = (i0 >> 3) & 3;
    const int bh = (i0 & 7) * 8 + (i0 >> 5);
    const int b = bh >> 4, h = bh & 15;
    const int t = threadIdx.x;
    const int lane = t & 63, w = t >> 6;    // 8 waves
    const int li = lane & 15, lg = lane >> 4;

    const unsigned short* Qb = Q + ((size_t)bh * SS << 7);
    const unsigned short* Kb = K + ((size_t)bh * SS << 7);
    const unsigned short* Vb = V + ((size_t)bh * SS << 7);
    const float SCL = 0.08838834764831845f; // 1/sqrt(128)

    u16x8 vreg[2];

    #pragma unroll 1
    for (int qi = 0; qi < 2; ++qi) {
        const int qt = qi ? (7 - bx) : bx;      // q-tiles of 256 rows
        const int q0 = qt * QB;
        const int qw = q0 + w * WQ;

        bf16x8 qa[2][4];
        #pragma unroll
        for (int rf = 0; rf < 2; ++rf)
            #pragma unroll
            for (int kq = 0; kq < 4; ++kq)
                qa[rf][kq] = __builtin_bit_cast(bf16x8,
                    *reinterpret_cast<const u16x8*>(&Qb[((size_t)(qw + rf*16 + li) << 7) + kq*32 + lg*8]));

        f32x4 oacc[2][8] = {};
        float lpart[2][4] = {};
        const int nt = (q0 + QB) / KVB;         // 4*qt + 4

        auto stageK = [&](int kv0, int which) {
            #pragma unroll
            for (int i = 0; i < 2; ++i) {
                const int slot0 = which * 1024 + i * 512 + w * 64;   // granules
                const int row = i * 32 + w * 4 + (lane >> 4);
                const int csrc = (lane & 15) ^ (row & 7);
                glds16(Kb + (((size_t)(kv0 + row)) << 7) + csrc * 8, &lds[slot0 * 8]);
            }
        };
        auto loadV = [&](int kv0) {
            const int row = lane;
            #pragma unroll
            for (int i = 0; i < 2; ++i) {
                const int dc = w + i * 8;       // 0..15 d-chunks across 8 waves
                vreg[i] = *reinterpret_cast<const u16x8*>(&Vb[(((size_t)(kv0 + row)) << 7) + dc * 8]);
            }
        };
        auto writeV = [&](int vbuf) {
            unsigned short* Vt = lds + 16384 + vbuf * 8192;
            #pragma unroll
            for (int i = 0; i < 2; ++i) {
                const int dc = w + i * 8;
                #pragma unroll
                for (int j = 0; j < 8; ++j) {
                    const int d = dc*8 + j;
                    Vt[d * 64 + (((lane >> 3) ^ (d & 7)) * 8) + (lane & 7)] = vreg[i][j];
                }
            }
        };

        stageK(0, 0);
        loadV(0);
        __syncthreads();
        writeV(0);
        __syncthreads();

        #pragma unroll 1
        for (int tt = 0; tt < nt; ++tt) {
            const int kv0 = tt * KVB;
            unsigned short* Kc = lds + (size_t)(tt & 1) * KSZ;
            const unsigned short* Vt = lds + 16384 + (tt & 1) * 8192;
            if (tt + 1 < nt) { stageK(kv0 + KVB, (tt & 1) ^ 1); loadV(kv0 + KVB); }

            if (kv0 <= qw + WQ - 1) {           // wave-level causal skip
                f32x4 sv[2][4] = {};
                __builtin_amdgcn_s_setprio(1);
                #pragma unroll
                for (int cf = 0; cf < 4; ++cf) {
                    const int krow = cf*16 + li;
                    #pragma unroll
                    for (int kq = 0; kq < 4; ++kq) {
                        bf16x8 kb = __builtin_bit_cast(bf16x8,
                            *reinterpret_cast<const u16x8*>(&Kc[krow * DK + (((kq*4 + lg) ^ (li & 7)) * 8)]));
                        #pragma unroll
                        for (int rf = 0; rf < 2; ++rf)
                            sv[rf][cf] = __builtin_amdgcn_mfma_f32_16x16x32_bf16(qa[rf][kq], kb, sv[rf][cf], 0, 0, 0);
                    }
                }
                __builtin_amdgcn_s_setprio(0);
                const bool diag = (kv0 + KVB - 1 > qw);
                #pragma unroll
                for (int rf = 0; rf < 2; ++rf)
                    #pragma unroll
                    for (int cf = 0; cf < 4; ++cf)
                        #pragma unroll
                        for (int r = 0; r < 4; ++r) {
                            float p = __expf(sv[rf][cf][r] * SCL);
                            if (diag) {
                                int rowg = qw + rf*16 + lg*4 + r;
                                int colg = kv0 + cf*16 + li;
                                p = (colg <= rowg) ? p : 0.0f;
                            }
                            sv[rf][cf][r] = p;
                            lpart[rf][r] += p;
                        }
                unsigned short* Pw = Pl + w * (WQ * 64);
                #pragma unroll
                for (int rf = 0; rf < 2; ++rf)
                    #pragma unroll
                    for (int cf = 0; cf < 4; ++cf)
                        #pragma unroll
                        for (int r = 0; r < 4; ++r) {
                            const int qr = rf*16 + lg*4 + r;
                            Pw[qr * 64 + (((cf*2 + (li >> 3)) ^ (qr & 7)) * 8) + (li & 7)] = f2bf(sv[rf][cf][r]);
                        }
                bf16x8 pa[2][2];
                #pragma unroll
                for (int rf = 0; rf < 2; ++rf)
                    #pragma unroll
                    for (int kc = 0; kc < 2; ++kc)
                        pa[rf][kc] = __builtin_bit_cast(bf16x8,
                            *reinterpret_cast<const u16x8*>(&Pw[(rf*16 + li) * 64 + (((kc*4 + lg) ^ (li & 7)) * 8)]));
                __builtin_amdgcn_s_setprio(1);
                #pragma unroll
                for (int g = 0; g < 8; ++g) {
                    const int vrow = g*16 + li;
                    bf16x8 vb0 = __builtin_bit_cast(bf16x8,
                        *reinterpret_cast<const u16x8*>(&Vt[vrow * 64 + ((lg ^ (li & 7)) * 8)]));
                    bf16x8 vb1 = __builtin_bit_cast(bf16x8,
                        *reinterpret_cast<const u16x8*>(&Vt[vrow * 64 + (((4 + lg) ^ (li & 7)) * 8)]));
                    #pragma unroll
                    for (int rf = 0; rf < 2; ++rf) {
                        oacc[rf][g] = __builtin_amdgcn_mfma_f32_16x16x32_bf16(pa[rf][0], vb0, oacc[rf][g], 0, 0, 0);
                        oacc[rf][g] = __builtin_amdgcn_mfma_f32_16x16x32_bf16(pa[rf][1], vb1, oacc[rf][g], 0, 0, 0);
                    }
                }
                __builtin_amdgcn_s_setprio(0);
            }

            if (tt + 1 < nt) writeV((tt + 1) & 1);   // idle buffer; auto vmcnt wait
            __syncthreads();                          // joins writeV + drains stageK
        }

        float ls[2][4];
        #pragma unroll
        for (int rf = 0; rf < 2; ++rf)
            #pragma unroll
            for (int r = 0; r < 4; ++r) {
                float s = lpart[rf][r];
                s += __shfl_xor(s, 1, 64);
                s += __shfl_xor(s, 2, 64);
                s += __shfl_xor(s, 4, 64);
                s += __shfl_xor(s, 8, 64);
                ls[rf][r] = 1.0f / s;
            }
        #pragma unroll
        for (int rf = 0; rf < 2; ++rf)
            #pragma unroll
            for (int g = 0; g < 8; ++g)
                #pragma unroll
                for (int r = 0; r < 4; ++r) {
                    int s = qw + rf*16 + lg*4 + r;
                    int d = g*16 + li;
                    AO[((size_t)b * SS + s) * D_MODEL + h*DK + d] = f2bf(oacc[rf][g][r] * ls[rf][r]);
                }
    }
}

// ---------------- host ----------------
extern "C" void kernel_launch(void* const* d_in, const int* in_sizes, int n_in,
                              void* d_out, int out_size, void* d_ws, size_t ws_size,
                              hipStream_t stream) {
    const float* x  = (const float*)d_in[0];
    const float* wq = (const float*)d_in[1];
    const float* wk = (const float*)d_in[2];
    const float* wv = (const float*)d_in[3];
    const float* wo = (const float*)d_in[4];
    const int* pos  = (const int*)d_in[5];

    char* ws = (char*)d_ws;
    size_t off = 0;
    auto alloc = [&](size_t bytes) {
        void* p = ws + off;
        off += (bytes + 255) & ~(size_t)255;
        return p;
    };
    const size_t XN = (size_t)MTOT * D_MODEL;   // 16,777,216
    const size_t WN = (size_t)D_MODEL * D_MODEL;
    unsigned short* xb    = (unsigned short*)alloc(XN * 2);
    unsigned short* wqkvb = (unsigned short*)alloc(3 * WN * 2);
    unsigned short* wob   = (unsigned short*)alloc(WN * 2);
    unsigned short* qkvb  = (unsigned short*)alloc(3 * XN * 2);
    unsigned short* qb = qkvb, *kb = qkvb + XN, *vb = qkvb + 2*XN;
    unsigned short* ao = xb;   // alias: xb dead after QKV GEMM

    cvt_all<<<32768, 256, 0, stream>>>(x, wq, wk, wv, wo, xb, wqkvb, wob);

    // merged QKV projection + fused RoPE: N = 6144, grid (24, 32) = 768 blocks
    gemm_bt<0><<<dim3(3*D_MODEL / GBN, MTOT / GBM), 512, 0, stream>>>(
        xb, wqkvb, qkvb, pos, MTOT, 3*D_MODEL, D_MODEL);

    attn_kernel<<<dim3(4, 64), 512, 0, stream>>>(qb, kb, vb, ao);

    gemm_bt<1><<<dim3(D_MODEL / GBN, MTOT / GBM), 512, 0, stream>>>(
        ao, wob, d_out, pos, MTOT, D_MODEL, D_MODEL);
}